// Round 3
// baseline (198.249 us; speedup 1.0000x reference)
//
#include <hip/hip_runtime.h>
#include <hip/hip_bf16.h>

// Flash-attention forward, block-causal (packed varlen docs).
// fp32 in HBM; bf16 MFMA internally. B=1, H=8, D=128.
// 1 block = (head, 32-row Q tile); 2 waves x 16 Q-rows; grid = 8*128 = 1024.
// K staged to LDS (double-buffered, 1 barrier/tile); V read directly from
// global (L2-resident, dense 64B segments) -- no LDS transpose, no conflicts.

#define HD 128
#define BR 32
#define BC 64
#define KSTRIDE (HD + 8)   // 136 elems = 272 B rows (16B-aligned, conflict-free b128 reads)
#define PSTRIDE (BC + 8)   // 72 elems = 144 B rows

typedef __attribute__((ext_vector_type(8))) short short8;
typedef __attribute__((ext_vector_type(4))) short short4v;
typedef __attribute__((ext_vector_type(4))) float floatx4;

__device__ inline short f2bf(float f) {
    __hip_bfloat16 b = __float2bfloat16(f);
    return *reinterpret_cast<short*>(&b);
}

__global__ __launch_bounds__(128, 4) void fa_fwd(
    const float* __restrict__ Q,
    const float* __restrict__ K,
    const float* __restrict__ V,
    const int* __restrict__ cu_seqlens, int n_cu,
    float* __restrict__ O,
    int S)
{
    __shared__ alignas(16) __hip_bfloat16 sK[2][BC * KSTRIDE];
    __shared__ alignas(16) __hip_bfloat16 sP[2][16 * PSTRIDE];

    const int tid  = threadIdx.x;
    const int wave = tid >> 6;     // 0..1
    const int lane = tid & 63;
    const int quad = lane >> 4;    // 0..3
    const int l16  = lane & 15;

    const int nqb = S / BR;
    const int h   = blockIdx.x / nqb;
    const int qb  = blockIdx.x % nqb;
    const int q0  = qb * BR;
    const int qw  = q0 + wave * 16;

    const size_t hoff = (size_t)h * S * HD;
    const float* Qh = Q + hoff;
    const float* Kh = K + hoff;
    const float* Vh = V + hoff;
    float*       Oh = O + hoff;

    // ---- per-row doc starts ----
    int doc_start[4];
    #pragma unroll
    for (int r = 0; r < 4; ++r) {
        int q = qw + quad * 4 + r;
        int dsr = 0;
        for (int i = 0; i < n_cu; ++i) {
            int c = cu_seqlens[i];
            if (c <= q) dsr = c;
        }
        doc_start[r] = dsr;
    }
    int blk_doc_start = 0;
    for (int i = 0; i < n_cu; ++i) {
        int c = cu_seqlens[i];
        if (c <= q0) blk_doc_start = c;
    }
    const int k_begin = blk_doc_start & ~(BC - 1);
    const int ntiles  = (q0 + BR - 1 - k_begin) / BC + 1;   // block-uniform

    // ---- Q fragments: A[m=l16][k = t*32 + quad*8 + j] ----
    short8 aq[4];
    {
        const float* qp = Qh + (size_t)(qw + l16) * HD + quad * 8;
        #pragma unroll
        for (int t = 0; t < 4; ++t) {
            float4 a0 = *(const float4*)(qp + t * 32);
            float4 a1 = *(const float4*)(qp + t * 32 + 4);
            short8 a;
            a[0] = f2bf(a0.x); a[1] = f2bf(a0.y); a[2] = f2bf(a0.z); a[3] = f2bf(a0.w);
            a[4] = f2bf(a1.x); a[5] = f2bf(a1.y); a[6] = f2bf(a1.z); a[7] = f2bf(a1.w);
            aq[t] = a;
        }
    }

    floatx4 oacc[8];
    #pragma unroll
    for (int dt = 0; dt < 8; ++dt) oacc[dt] = (floatx4){0.f, 0.f, 0.f, 0.f};
    float m_r[4], l_r[4];
    #pragma unroll
    for (int r = 0; r < 4; ++r) { m_r[r] = -1e30f; l_r[r] = 0.f; }

    const float sl = 0.08838834764831845f * 1.4426950408889634f;  // scale * log2(e)

    __hip_bfloat16* pbuf = &sP[wave][0];

    // ---- K tile staging: fp32 global -> bf16 LDS, 128 threads ----
    auto stage = [&](int kb, int kt) {
        const float* base = Kh + (size_t)kt * HD;
        __hip_bfloat16* dst = &sK[kb][0];
        #pragma unroll
        for (int p = 0; p < 16; ++p) {
            const int idx4 = p * 128 + tid;
            const int row  = idx4 >> 5;          // 32 float4 per row
            const int c    = (idx4 & 31) * 4;
            float4 fk = *(const float4*)(base + row * HD + c);
            short4v hk;
            hk[0] = f2bf(fk.x); hk[1] = f2bf(fk.y); hk[2] = f2bf(fk.z); hk[3] = f2bf(fk.w);
            *(short4v*)(&dst[row * KSTRIDE + c]) = hk;
        }
    };

    stage(0, k_begin);
    __syncthreads();

    for (int it = 0; it < ntiles; ++it) {
        const int kt = k_begin + it * BC;
        const int kb = it & 1;

        // prefetch next K tile into the other buffer (no extra barrier: the
        // end-of-iteration barrier publishes it)
        if (it + 1 < ntiles) stage(kb ^ 1, kt + BC);

        const __hip_bfloat16* sKb = &sK[kb][0];

        // ---- S = Q K^T : 16 rows x 64 keys ----
        floatx4 sc[4];
        #pragma unroll
        for (int ct = 0; ct < 4; ++ct) {
            floatx4 c = (floatx4){0.f, 0.f, 0.f, 0.f};
            #pragma unroll
            for (int ks = 0; ks < 4; ++ks) {
                short8 b = *(const short8*)(&sKb[(ct * 16 + l16) * KSTRIDE + ks * 32 + quad * 8]);
                c = __builtin_amdgcn_mfma_f32_16x16x32_bf16(aq[ks], b, c, 0, 0, 0);
            }
            sc[ct] = c;
        }

        // ---- scale + mask (C layout: row = quad*4+r, col = ct*16+l16) ----
        #pragma unroll
        for (int ct = 0; ct < 4; ++ct) {
            const int key = kt + ct * 16 + l16;
            #pragma unroll
            for (int r = 0; r < 4; ++r) {
                const int q = qw + quad * 4 + r;
                const bool valid = (key <= q) && (key >= doc_start[r]);
                float s = sc[ct][r] * sl;
                sc[ct][r] = valid ? s : -1e30f;
            }
        }

        // ---- online softmax, phase-structured for ILP ----
        float mx[4];
        #pragma unroll
        for (int r = 0; r < 4; ++r)
            mx[r] = fmaxf(fmaxf(sc[0][r], sc[1][r]), fmaxf(sc[2][r], sc[3][r]));
        #pragma unroll
        for (int off = 1; off < 16; off <<= 1) {
            #pragma unroll
            for (int r = 0; r < 4; ++r)
                mx[r] = fmaxf(mx[r], __shfl_xor(mx[r], off, 64));
        }
        float al[4];
        #pragma unroll
        for (int r = 0; r < 4; ++r) {
            const float mnew = fmaxf(m_r[r], mx[r]);
            al[r] = exp2f(m_r[r] - mnew);
            m_r[r] = mnew;
        }
        float ps[4];
        #pragma unroll
        for (int r = 0; r < 4; ++r) {
            float s0 = exp2f(sc[0][r] - m_r[r]);   // -1e30 path underflows to 0
            float s1 = exp2f(sc[1][r] - m_r[r]);
            float s2 = exp2f(sc[2][r] - m_r[r]);
            float s3 = exp2f(sc[3][r] - m_r[r]);
            sc[0][r] = s0; sc[1][r] = s1; sc[2][r] = s2; sc[3][r] = s3;
            ps[r] = (s0 + s1) + (s2 + s3);
        }
        #pragma unroll
        for (int off = 1; off < 16; off <<= 1) {
            #pragma unroll
            for (int r = 0; r < 4; ++r)
                ps[r] += __shfl_xor(ps[r], off, 64);
        }
        #pragma unroll
        for (int r = 0; r < 4; ++r)
            l_r[r] = l_r[r] * al[r] + ps[r];
        #pragma unroll
        for (int dt = 0; dt < 8; ++dt) {
            #pragma unroll
            for (int r = 0; r < 4; ++r)
                oacc[dt][r] *= al[r];
        }

        // ---- P (C layout) -> wave-private LDS -> A layout (no barrier) ----
        #pragma unroll
        for (int ct = 0; ct < 4; ++ct)
            #pragma unroll
            for (int r = 0; r < 4; ++r)
                pbuf[(quad * 4 + r) * PSTRIDE + ct * 16 + l16] = __float2bfloat16(sc[ct][r]);

        // ---- O += P V ; V B-frags straight from global (L2-hot) ----
        #pragma unroll
        for (int ks = 0; ks < 2; ++ks) {
            short8 ap = *(const short8*)(&pbuf[l16 * PSTRIDE + ks * 32 + quad * 8]);
            const float* vb = Vh + (size_t)(kt + ks * 32 + quad * 8) * HD + l16;
            #pragma unroll
            for (int dt = 0; dt < 8; ++dt) {
                float f0 = vb[0 * HD + dt * 16];
                float f1 = vb[1 * HD + dt * 16];
                float f2 = vb[2 * HD + dt * 16];
                float f3 = vb[3 * HD + dt * 16];
                float f4 = vb[4 * HD + dt * 16];
                float f5 = vb[5 * HD + dt * 16];
                float f6 = vb[6 * HD + dt * 16];
                float f7 = vb[7 * HD + dt * 16];
                short8 bv;
                bv[0] = f2bf(f0); bv[1] = f2bf(f1); bv[2] = f2bf(f2); bv[3] = f2bf(f3);
                bv[4] = f2bf(f4); bv[5] = f2bf(f5); bv[6] = f2bf(f6); bv[7] = f2bf(f7);
                oacc[dt] = __builtin_amdgcn_mfma_f32_16x16x32_bf16(ap, bv, oacc[dt], 0, 0, 0);
            }
        }

        __syncthreads();   // publish prefetched sK, protect old buffer
    }

    // ---- epilogue: normalize, store fp32 ----
    #pragma unroll
    for (int r = 0; r < 4; ++r) {
        const float inv = 1.0f / l_r[r];
        float* op = Oh + (size_t)(qw + quad * 4 + r) * HD;
        #pragma unroll
        for (int dt = 0; dt < 8; ++dt)
            op[dt * 16 + l16] = oacc[dt][r] * inv;
    }
}

extern "C" void kernel_launch(void* const* d_in, const int* in_sizes, int n_in,
                              void* d_out, int out_size, void* d_ws, size_t ws_size,
                              hipStream_t stream) {
    const float* q = (const float*)d_in[0];
    const float* k = (const float*)d_in[1];
    const float* v = (const float*)d_in[2];
    const int* cu = (const int*)d_in[3];
    const int n_cu = in_sizes[3];
    const int H = 8;
    const int S = in_sizes[0] / (H * HD);   // B=1
    float* out = (float*)d_out;

    dim3 grid(H * (S / BR));
    dim3 block(128);
    fa_fwd<<<grid, block, 0, stream>>>(q, k, v, cu, n_cu, out, S);
}